// Round 4
// baseline (442.101 us; speedup 1.0000x reference)
//
#include <hip/hip_runtime.h>
#include <math.h>

#define NN 50000
#define NE 800000
#define BSHIFT 7
#define BNODES 128                      // nodes per bucket
#define NB 391                          // ceil(NN / BNODES)
#define NBB 200                         // binning blocks
#define EPB 4000                        // edges per binning block (NBB*EPB == NE)

__device__ __forceinline__ unsigned fkey(float f) {
    unsigned u = __float_as_uint(f);
    return (u & 0x80000000u) ? ~u : (u | 0x80000000u);
}
__device__ __forceinline__ float funkey(unsigned k) {
    unsigned u = (k & 0x80000000u) ? (k & 0x7FFFFFFFu) : ~k;
    return __uint_as_float(u);
}
__device__ __forceinline__ float elu1(float v) {
    return v > 0.0f ? v : expm1f(v);
}

// ---- pass 1: per-block histogram over NB buckets ----
__global__ void bin1_kernel(const int* __restrict__ ei, int* __restrict__ HM) {
    __shared__ unsigned hist[NB];
    for (int i = threadIdx.x; i < NB; i += 256) hist[i] = 0;
    __syncthreads();
    int base = blockIdx.x * EPB;
    for (int i = threadIdx.x; i < EPB; i += 256) {
        int d = ei[NE + base + i];
        atomicAdd(&hist[d >> BSHIFT], 1u);
    }
    __syncthreads();
    for (int b = threadIdx.x; b < NB; b += 256)
        HM[b * NBB + blockIdx.x] = (int)hist[b];
}

// ---- pass 2: scan HM (bin-major) in place -> per-(bin,block) bases; bucket starts ----
__global__ void scan_bins_kernel(int* __restrict__ HM, int* __restrict__ bstart) {
    __shared__ int s[512];
    int t = threadIdx.x;
    int v = 0;
    if (t < NB) {
        for (int k = 0; k < NBB; ++k) v += HM[t * NBB + k];
    }
    s[t] = v;
    __syncthreads();
#pragma unroll
    for (int off = 1; off < 512; off <<= 1) {
        int tmp = (t >= off) ? s[t - off] : 0;
        __syncthreads();
        s[t] += tmp;
        __syncthreads();
    }
    int excl = s[t] - v;
    if (t < NB) {
        bstart[t] = excl;
        int running = excl;
        for (int k = 0; k < NBB; ++k) {
            int c = HM[t * NBB + k];
            HM[t * NBB + k] = running;
            running += c;
        }
    }
    if (t == 0) bstart[NB] = s[511];
}

// ---- pass 3: scatter records into bucket-grouped array (LDS cursors, no global atomics) ----
__global__ void bin2_kernel(const int* __restrict__ ei, const float* __restrict__ ea,
                            const int* __restrict__ HM, int2* __restrict__ sp) {
    __shared__ unsigned cur[NB];
    for (int b = threadIdx.x; b < NB; b += 256)
        cur[b] = (unsigned)HM[b * NBB + blockIdx.x];
    __syncthreads();
    int base = blockIdx.x * EPB;
    for (int i = threadIdx.x; i < EPB; i += 256) {
        int e = base + i;
        int d = ei[NE + e];
        int srcv = ei[e];
        int b = d >> BSHIFT;
        int dl = d & (BNODES - 1);
        unsigned pos = atomicAdd(&cur[b], 1u);
        sp[pos] = make_int2(srcv | (dl << 16), __float_as_int(ea[e]));
    }
}

// ---- node pre-projection (layer 1): P1 = x @ Wp[:64] + bp ----
__global__ void pre1_kernel(const float* __restrict__ x,
                            const float* __restrict__ Wp,   // [65][16]
                            const float* __restrict__ bp,   // [16]
                            float* __restrict__ P1) {
    __shared__ float sW[64 * 16];
    __shared__ float sb[16];
    for (int i = threadIdx.x; i < 64 * 16; i += blockDim.x) sW[i] = Wp[i];
    if (threadIdx.x < 16) sb[threadIdx.x] = bp[threadIdx.x];
    __syncthreads();
    int n = blockIdx.x * blockDim.x + threadIdx.x;
    if (n >= NN) return;
    float acc[16];
#pragma unroll
    for (int k = 0; k < 16; ++k) acc[k] = sb[k];
    const float4* xr = (const float4*)(x + (size_t)n * 64);
#pragma unroll
    for (int j4 = 0; j4 < 16; ++j4) {
        float4 xv = xr[j4];
        const float* w = &sW[j4 * 4 * 16];
#pragma unroll
        for (int k = 0; k < 16; ++k) acc[k] += xv.x * w[k];
#pragma unroll
        for (int k = 0; k < 16; ++k) acc[k] += xv.y * w[16 + k];
#pragma unroll
        for (int k = 0; k < 16; ++k) acc[k] += xv.z * w[32 + k];
#pragma unroll
        for (int k = 0; k < 16; ++k) acc[k] += xv.w * w[48 + k];
    }
    float4* o = (float4*)(P1 + (size_t)n * 16);
    o[0] = make_float4(acc[0], acc[1], acc[2], acc[3]);
    o[1] = make_float4(acc[4], acc[5], acc[6], acc[7]);
    o[2] = make_float4(acc[8], acc[9], acc[10], acc[11]);
    o[3] = make_float4(acc[12], acc[13], acc[14], acc[15]);
}

// ---- fused per-bucket gather-max (LDS) + node MLP ----
// MODE 0: agg -> @Wo+bo -> elu(elu) -> @Wpn+bpn -> out (=P2)
// MODE 1: agg -> @Wo+bo -> log_softmax -> out
template <int MODE>
__global__ void gather_kernel(const int2* __restrict__ sp,
                              const int* __restrict__ bstart,  // [NB+1]
                              const float* __restrict__ Pin,   // [NN][16]
                              const float* __restrict__ wl,    // [16]
                              const float* __restrict__ Wn,    // [16][16]
                              const float* __restrict__ bn,    // [16]
                              const float* __restrict__ Wo,    // [16][16]
                              const float* __restrict__ bo,    // [16]
                              const float* __restrict__ Wpn,   // [17][16] (MODE 0)
                              const float* __restrict__ bpn,   // [16] (MODE 0)
                              float* __restrict__ out) {
    __shared__ unsigned sAgg[BNODES][17];   // padded: stride 17 words -> conflict-free
    __shared__ float sH[BNODES][17];
    __shared__ float sWn[256], sWo[256], sWpn[256];
    __shared__ float swl[16], sbn[16], sbo[16], sbpn[16];
    int tid = threadIdx.x;
    if (tid < 256) {
        sWn[tid] = Wn[tid];
        sWo[tid] = Wo[tid];
        if (MODE == 0) sWpn[tid] = Wpn[tid];
    }
    if (tid < 16) {
        swl[tid] = wl[tid]; sbn[tid] = bn[tid]; sbo[tid] = bo[tid];
        if (MODE == 0) sbpn[tid] = bpn[tid];
    }
    for (int i = tid; i < BNODES * 17; i += 256) ((unsigned*)sAgg)[i] = 0u;
    __syncthreads();

    int b = blockIdx.x;
    int e0 = bstart[b], e1 = bstart[b + 1];
    for (int i = e0 + tid; i < e1; i += 256) {
        int2 rec = sp[i];
        int src = rec.x & 0xFFFF;
        int dl = (rec.x >> 16) & (BNODES - 1);
        float a = __int_as_float(rec.y);
        const float4* pr = (const float4*)(Pin + (size_t)src * 16);
        float4 v0 = pr[0], v1 = pr[1], v2 = pr[2], v3 = pr[3];
        float t[16] = {v0.x, v0.y, v0.z, v0.w, v1.x, v1.y, v1.z, v1.w,
                       v2.x, v2.y, v2.z, v2.w, v3.x, v3.y, v3.z, v3.w};
#pragma unroll
        for (int j = 0; j < 16; ++j) t[j] = fmaxf(fmaf(a, swl[j], t[j]), 0.0f);
#pragma unroll
        for (int k = 0; k < 16; ++k) {
            float m = sbn[k];
#pragma unroll
            for (int j = 0; j < 16; ++j) m = fmaf(t[j], sWn[j * 16 + k], m);
            atomicMax(&sAgg[dl][k], fkey(m));
        }
    }
    __syncthreads();

    // epilogue: 2 threads per node (8 dims each)
    int l = tid >> 1;            // local node 0..127
    int half = tid & 1;          // dim half
    int n = b * BNODES + l;
    bool valid = (n < NN);

    float g[16];
#pragma unroll
    for (int j = 0; j < 16; ++j) {
        float v = funkey(sAgg[l][j]);
        g[j] = isfinite(v) ? v : 0.0f;
    }
    float h[8];
#pragma unroll
    for (int q = 0; q < 8; ++q) {
        int c = half * 8 + q;
        float o = sbo[c];
#pragma unroll
        for (int j = 0; j < 16; ++j) o = fmaf(g[j], sWo[j * 16 + c], o);
        h[q] = o;
    }

    if (MODE == 0) {
#pragma unroll
        for (int q = 0; q < 8; ++q) sH[l][half * 8 + q] = elu1(elu1(h[q]));
        __syncthreads();
        float p[8];
#pragma unroll
        for (int q = 0; q < 8; ++q) {
            int c = half * 8 + q;
            float o = sbpn[c];
#pragma unroll
            for (int k = 0; k < 16; ++k) o = fmaf(sH[l][k], sWpn[k * 16 + c], o);
            p[q] = o;
        }
        if (valid) {
            float4* op = (float4*)(out + (size_t)n * 16 + half * 8);
            op[0] = make_float4(p[0], p[1], p[2], p[3]);
            op[1] = make_float4(p[4], p[5], p[6], p[7]);
        }
    } else {
#pragma unroll
        for (int q = 0; q < 8; ++q) sH[l][half * 8 + q] = h[q];
        __syncthreads();
        float mx = -INFINITY;
#pragma unroll
        for (int j = 0; j < 16; ++j) mx = fmaxf(mx, sH[l][j]);
        float sum = 0.0f;
#pragma unroll
        for (int j = 0; j < 16; ++j) sum += expf(sH[l][j] - mx);
        float ls = logf(sum) + mx;
        if (valid) {
            float4* op = (float4*)(out + (size_t)n * 16 + half * 8);
            op[0] = make_float4(h[0] - ls, h[1] - ls, h[2] - ls, h[3] - ls);
            op[1] = make_float4(h[4] - ls, h[5] - ls, h[6] - ls, h[7] - ls);
        }
    }
}

extern "C" void kernel_launch(void* const* d_in, const int* in_sizes, int n_in,
                              void* d_out, int out_size, void* d_ws, size_t ws_size,
                              hipStream_t stream) {
    const float* x         = (const float*)d_in[0];
    const float* edge_attr = (const float*)d_in[1];
    const int*   edge_index= (const int*)  d_in[2];
    const float* W_pre1 = (const float*)d_in[3];
    const float* b_pre1 = (const float*)d_in[4];
    const float* W_net1 = (const float*)d_in[5];
    const float* b_net1 = (const float*)d_in[6];
    const float* W_out1 = (const float*)d_in[7];
    const float* b_out1 = (const float*)d_in[8];
    const float* W_pre2 = (const float*)d_in[9];
    const float* b_pre2 = (const float*)d_in[10];
    const float* W_net2 = (const float*)d_in[11];
    const float* b_net2 = (const float*)d_in[12];
    const float* W_out2 = (const float*)d_in[13];
    const float* b_out2 = (const float*)d_in[14];

    char* ws = (char*)d_ws;
    float* P1     = (float*)(ws);                       // 3,200,000 B
    float* P2     = (float*)(ws + 3200000);             // 3,200,000 B
    int2*  sp     = (int2*) (ws + 6400000);             // 6,400,000 B
    int*   HM     = (int*)  (ws + 12800000);            // NB*NBB*4 = 312,800 B
    int*   bstart = (int*)  (ws + 13112800);            // (NB+1)*4 = 1,568 B

    const int NODE_BLOCKS = (NN + 255) / 256;   // 196

    // ----- bucket-grouped edge list (shared by both layers), no global atomics -----
    bin1_kernel<<<NBB, 256, 0, stream>>>(edge_index, HM);
    scan_bins_kernel<<<1, 512, 0, stream>>>(HM, bstart);
    bin2_kernel<<<NBB, 256, 0, stream>>>(edge_index, edge_attr, HM, sp);

    // ----- layer 1 -----
    pre1_kernel<<<NODE_BLOCKS, 256, 0, stream>>>(x, W_pre1, b_pre1, P1);
    gather_kernel<0><<<NB, 256, 0, stream>>>(sp, bstart, P1,
        W_pre1 + 64 * 16, W_net1, b_net1, W_out1, b_out1, W_pre2, b_pre2, P2);

    // ----- layer 2 -----
    gather_kernel<1><<<NB, 256, 0, stream>>>(sp, bstart, P2,
        W_pre2 + 16 * 16, W_net2, b_net2, W_out2, b_out2, nullptr, nullptr,
        (float*)d_out);
}

// Round 5
// 122.763 us; speedup vs baseline: 3.6013x; 3.6013x over previous
//
#include <hip/hip_runtime.h>
#include <math.h>

#define NN 50000
#define NE 800000
#define BSHIFT 7
#define BNODES 128                      // nodes per bucket
#define NB 391                          // ceil(NN / BNODES)
#define NBB 200                         // binning blocks
#define EPB 4000                        // edges per binning block (NBB*EPB == NE)

__device__ __forceinline__ float elu1(float v) {
    return v > 0.0f ? v : expm1f(v);
}

// ---- pass 1: per-block histogram over NB buckets ----
__global__ void bin1_kernel(const int* __restrict__ ei, int* __restrict__ HM) {
    __shared__ unsigned hist[NB];
    for (int i = threadIdx.x; i < NB; i += 256) hist[i] = 0;
    __syncthreads();
    int base = blockIdx.x * EPB;
    for (int i = threadIdx.x; i < EPB; i += 256) {
        int d = ei[NE + base + i];
        atomicAdd(&hist[d >> BSHIFT], 1u);
    }
    __syncthreads();
    for (int b = threadIdx.x; b < NB; b += 256)
        HM[b * NBB + blockIdx.x] = (int)hist[b];
}

// ---- pass 2: scan HM (bin-major) in place -> per-(bin,block) bases; bucket starts ----
__global__ void scan_bins_kernel(int* __restrict__ HM, int* __restrict__ bstart) {
    __shared__ int s[512];
    int t = threadIdx.x;
    int v = 0;
    if (t < NB) {
        for (int k = 0; k < NBB; ++k) v += HM[t * NBB + k];
    }
    s[t] = v;
    __syncthreads();
#pragma unroll
    for (int off = 1; off < 512; off <<= 1) {
        int tmp = (t >= off) ? s[t - off] : 0;
        __syncthreads();
        s[t] += tmp;
        __syncthreads();
    }
    int excl = s[t] - v;
    if (t < NB) {
        bstart[t] = excl;
        int running = excl;
        for (int k = 0; k < NBB; ++k) {
            int c = HM[t * NBB + k];
            HM[t * NBB + k] = running;
            running += c;
        }
    }
    if (t == 0) bstart[NB] = s[511];
}

// ---- pass 3: scatter records into bucket-grouped array (LDS cursors) ----
__global__ void bin2_kernel(const int* __restrict__ ei, const float* __restrict__ ea,
                            const int* __restrict__ HM, int2* __restrict__ sp1) {
    __shared__ unsigned cur[NB];
    for (int b = threadIdx.x; b < NB; b += 256)
        cur[b] = (unsigned)HM[b * NBB + blockIdx.x];
    __syncthreads();
    int base = blockIdx.x * EPB;
    for (int i = threadIdx.x; i < EPB; i += 256) {
        int e = base + i;
        int d = ei[NE + e];
        int srcv = ei[e];
        int b = d >> BSHIFT;
        int dl = d & (BNODES - 1);
        unsigned pos = atomicAdd(&cur[b], 1u);
        sp1[pos] = make_int2(srcv | (dl << 16), __float_as_int(ea[e]));
    }
}

// ---- pass 4: per-bucket counting sort by local node; emit node-sorted sp2 + start[] ----
__global__ void sort_kernel(const int2* __restrict__ sp1,
                            const int* __restrict__ bstart,
                            int2* __restrict__ sp2,
                            int* __restrict__ start) {
    __shared__ unsigned hist[BNODES];
    __shared__ unsigned cur[BNODES];
    __shared__ int s[256];
    int tid = threadIdx.x;
    int b = blockIdx.x;
    int e0 = bstart[b], e1 = bstart[b + 1];
    if (tid < BNODES) hist[tid] = 0;
    __syncthreads();
    for (int i = e0 + tid; i < e1; i += 256) {
        int dl = (sp1[i].x >> 16) & (BNODES - 1);
        atomicAdd(&hist[dl], 1u);
    }
    __syncthreads();
    int v = (tid < BNODES) ? (int)hist[tid] : 0;
    s[tid] = v;
    __syncthreads();
#pragma unroll
    for (int off = 1; off < 256; off <<= 1) {
        int t = (tid >= off) ? s[tid - off] : 0;
        __syncthreads();
        s[tid] += t;
        __syncthreads();
    }
    if (tid < BNODES) {
        int excl = s[tid] - v;
        cur[tid] = (unsigned)excl;
        start[b * BNODES + tid] = e0 + excl;
    }
    __syncthreads();
    for (int i = e0 + tid; i < e1; i += 256) {
        int2 rec = sp1[i];
        int dl = (rec.x >> 16) & (BNODES - 1);
        int pos = e0 + (int)atomicAdd(&cur[dl], 1u);
        sp2[pos] = make_int2(rec.x & 0xFFFF, rec.y);
    }
}

// ---- node pre-projection (layer 1): P1 = x @ Wp[:64] + bp ----
__global__ void pre1_kernel(const float* __restrict__ x,
                            const float* __restrict__ Wp,   // [65][16]
                            const float* __restrict__ bp,   // [16]
                            float* __restrict__ P1) {
    __shared__ float sW[64 * 16];
    __shared__ float sb[16];
    for (int i = threadIdx.x; i < 64 * 16; i += blockDim.x) sW[i] = Wp[i];
    if (threadIdx.x < 16) sb[threadIdx.x] = bp[threadIdx.x];
    __syncthreads();
    int n = blockIdx.x * blockDim.x + threadIdx.x;
    if (n >= NN) return;
    float acc[16];
#pragma unroll
    for (int k = 0; k < 16; ++k) acc[k] = sb[k];
    const float4* xr = (const float4*)(x + (size_t)n * 64);
#pragma unroll
    for (int j4 = 0; j4 < 16; ++j4) {
        float4 xv = xr[j4];
        const float* w = &sW[j4 * 4 * 16];
#pragma unroll
        for (int k = 0; k < 16; ++k) acc[k] += xv.x * w[k];
#pragma unroll
        for (int k = 0; k < 16; ++k) acc[k] += xv.y * w[16 + k];
#pragma unroll
        for (int k = 0; k < 16; ++k) acc[k] += xv.z * w[32 + k];
#pragma unroll
        for (int k = 0; k < 16; ++k) acc[k] += xv.w * w[48 + k];
    }
    float4* o = (float4*)(P1 + (size_t)n * 16);
    o[0] = make_float4(acc[0], acc[1], acc[2], acc[3]);
    o[1] = make_float4(acc[4], acc[5], acc[6], acc[7]);
    o[2] = make_float4(acc[8], acc[9], acc[10], acc[11]);
    o[3] = make_float4(acc[12], acc[13], acc[14], acc[15]);
}

// ---- fused gather-max + node MLP (atomic-free, 4 threads/node) ----
template <int MODE>
__global__ void gather_kernel(const int2* __restrict__ sp,     // [NE] node-sorted
                              const int* __restrict__ start,   // [NB*BNODES+1]
                              const float* __restrict__ Pin,   // [NN][16]
                              const float* __restrict__ wl,    // [16]
                              const float* __restrict__ Wn,    // [16][16]
                              const float* __restrict__ bn,    // [16]
                              const float* __restrict__ Wo,    // [16][16]
                              const float* __restrict__ bo,    // [16]
                              const float* __restrict__ Wpn,   // [17][16] (MODE 0)
                              const float* __restrict__ bpn,   // [16] (MODE 0)
                              float* __restrict__ out) {
    __shared__ float swl[16], sbn[16], sbo[16], sbpn[16];
    __shared__ float sWn[256], sWo[256], sWpn[256];
    __shared__ float sAgg[64][17];
    int tid = threadIdx.x;
    if (tid < 256) {
        sWn[tid] = Wn[tid];
        sWo[tid] = Wo[tid];
        if (MODE == 0) sWpn[tid] = Wpn[tid];
    }
    if (tid < 16) {
        swl[tid] = wl[tid]; sbn[tid] = bn[tid]; sbo[tid] = bo[tid];
        if (MODE == 0) sbpn[tid] = bpn[tid];
    }
    __syncthreads();

    int l = tid >> 2;        // local node 0..63
    int g = tid & 3;         // dim group 0..3
    int n = blockIdx.x * 64 + l;
    bool valid = (n < NN);

    float acc[4] = {-INFINITY, -INFINITY, -INFINITY, -INFINITY};
    int s0 = 0, s1 = 0;
    if (valid) { s0 = start[n]; s1 = start[n + 1]; }

    int s = s0;
    int2 rec = (s < s1) ? sp[s] : make_int2(0, 0);
    float4 p0, p1, p2, p3;
    if (s < s1) {
        const float4* pr = (const float4*)(Pin + (size_t)rec.x * 16);
        p0 = pr[0]; p1 = pr[1]; p2 = pr[2]; p3 = pr[3];
    }
    while (s < s1) {
        float a = __int_as_float(rec.y);
        float4 c0 = p0, c1 = p1, c2 = p2, c3 = p3;
        ++s;
        if (s < s1) {                    // software pipeline: next record + next P
            rec = sp[s];
            const float4* pr = (const float4*)(Pin + (size_t)rec.x * 16);
            p0 = pr[0]; p1 = pr[1]; p2 = pr[2]; p3 = pr[3];
        }
        float t[16] = {c0.x, c0.y, c0.z, c0.w, c1.x, c1.y, c1.z, c1.w,
                       c2.x, c2.y, c2.z, c2.w, c3.x, c3.y, c3.z, c3.w};
#pragma unroll
        for (int j = 0; j < 16; ++j) t[j] = fmaxf(fmaf(a, swl[j], t[j]), 0.0f);
#pragma unroll
        for (int q = 0; q < 4; ++q) {
            int c = g * 4 + q;
            float m = sbn[c];
#pragma unroll
            for (int j = 0; j < 16; ++j) m = fmaf(t[j], sWn[j * 16 + c], m);
            acc[q] = fmaxf(acc[q], m);
        }
    }
    bool empty = (s1 == s0);
#pragma unroll
    for (int q = 0; q < 4; ++q) sAgg[l][g * 4 + q] = empty ? 0.0f : acc[q];
    __syncthreads();

    if (MODE == 0) {
        float h[4];
#pragma unroll
        for (int q = 0; q < 4; ++q) {
            int c = g * 4 + q;
            float o = sbo[c];
#pragma unroll
            for (int j = 0; j < 16; ++j) o = fmaf(sAgg[l][j], sWo[j * 16 + c], o);
            h[q] = elu1(elu1(o));
        }
        __syncthreads();
#pragma unroll
        for (int q = 0; q < 4; ++q) sAgg[l][g * 4 + q] = h[q];
        __syncthreads();
        float p[4];
#pragma unroll
        for (int q = 0; q < 4; ++q) {
            int c = g * 4 + q;
            float o = sbpn[c];
#pragma unroll
            for (int k = 0; k < 16; ++k) o = fmaf(sAgg[l][k], sWpn[k * 16 + c], o);
            p[q] = o;
        }
        if (valid) {
            float4* op = (float4*)(out + (size_t)n * 16 + g * 4);
            *op = make_float4(p[0], p[1], p[2], p[3]);
        }
    } else {
        float oo[4];
#pragma unroll
        for (int q = 0; q < 4; ++q) {
            int c = g * 4 + q;
            float o = sbo[c];
#pragma unroll
            for (int j = 0; j < 16; ++j) o = fmaf(sAgg[l][j], sWo[j * 16 + c], o);
            oo[q] = o;
        }
        __syncthreads();
#pragma unroll
        for (int q = 0; q < 4; ++q) sAgg[l][g * 4 + q] = oo[q];
        __syncthreads();
        float mx = -INFINITY;
#pragma unroll
        for (int j = 0; j < 16; ++j) mx = fmaxf(mx, sAgg[l][j]);
        float sum = 0.0f;
#pragma unroll
        for (int j = 0; j < 16; ++j) sum += expf(sAgg[l][j] - mx);
        float ls = logf(sum) + mx;
        if (valid) {
            float4* op = (float4*)(out + (size_t)n * 16 + g * 4);
            *op = make_float4(oo[0] - ls, oo[1] - ls, oo[2] - ls, oo[3] - ls);
        }
    }
}

extern "C" void kernel_launch(void* const* d_in, const int* in_sizes, int n_in,
                              void* d_out, int out_size, void* d_ws, size_t ws_size,
                              hipStream_t stream) {
    const float* x         = (const float*)d_in[0];
    const float* edge_attr = (const float*)d_in[1];
    const int*   edge_index= (const int*)  d_in[2];
    const float* W_pre1 = (const float*)d_in[3];
    const float* b_pre1 = (const float*)d_in[4];
    const float* W_net1 = (const float*)d_in[5];
    const float* b_net1 = (const float*)d_in[6];
    const float* W_out1 = (const float*)d_in[7];
    const float* b_out1 = (const float*)d_in[8];
    const float* W_pre2 = (const float*)d_in[9];
    const float* b_pre2 = (const float*)d_in[10];
    const float* W_net2 = (const float*)d_in[11];
    const float* b_net2 = (const float*)d_in[12];
    const float* W_out2 = (const float*)d_in[13];
    const float* b_out2 = (const float*)d_in[14];

    char* ws = (char*)d_ws;
    int2*  sp1    = (int2*) (ws);                       // 6,400,000 B (dead after sort)
    int2*  sp2    = (int2*) (ws + 6400000);             // 6,400,000 B
    int*   HM     = (int*)  (ws + 12800000);            // 312,800 B
    int*   bstart = (int*)  (ws + 13112800);            // 1,568 B
    int*   start  = (int*)  (ws + 13114368);            // (NB*128+1)*4 = 200,196 B
    float* P1     = (float*)(ws);                       // aliases sp1 (3.2 MB)
    float* P2     = (float*)(ws + 3200000);             // aliases sp1 upper half

    const int NODE_BLOCKS = (NN + 255) / 256;   // 196
    const int GATH_BLOCKS = (NN + 63) / 64;     // 782

    // ----- node-sorted edge list via two-level counting sort (no global atomics) -----
    bin1_kernel<<<NBB, 256, 0, stream>>>(edge_index, HM);
    scan_bins_kernel<<<1, 512, 0, stream>>>(HM, bstart);
    bin2_kernel<<<NBB, 256, 0, stream>>>(edge_index, edge_attr, HM, sp1);
    sort_kernel<<<NB, 256, 0, stream>>>(sp1, bstart, sp2, start);

    // ----- layer 1 -----
    pre1_kernel<<<NODE_BLOCKS, 256, 0, stream>>>(x, W_pre1, b_pre1, P1);
    gather_kernel<0><<<GATH_BLOCKS, 256, 0, stream>>>(sp2, start, P1,
        W_pre1 + 64 * 16, W_net1, b_net1, W_out1, b_out1, W_pre2, b_pre2, P2);

    // ----- layer 2 -----
    gather_kernel<1><<<GATH_BLOCKS, 256, 0, stream>>>(sp2, start, P2,
        W_pre2 + 16 * 16, W_net2, b_net2, W_out2, b_out2, nullptr, nullptr,
        (float*)d_out);
}